// Round 5
// baseline (366.198 us; speedup 1.0000x reference)
//
#include <hip/hip_runtime.h>
#include <math.h>

#define T_ 8
#define B_ 4
#define C_ 128
#define HW_ 9216        // 96*96
#define IN_HW_ 147456   // 384*384
#define NCHUNK 9        // pixel chunks in k_gs: 9216/4/9 = 256 float4 per chunk
#define VPART 36        // v_sum partials per tb (HW_/256)

// ---------------------------------------------------------------------------
// Bilinear antialias resize 384 -> 96: separable 8-tap triangle filter.
// Raw w_k = {.125,.375,.625,.875,.875,.625,.375,.125}/4; edges renormalized
// over valid taps (/3.5). fp64 to match the numpy reference on knife-edge
// pixels (the >0.5 threshold sits in the bulk of the resized distribution).
// ---------------------------------------------------------------------------
__device__ __forceinline__ double resize_px(const float* __restrict__ img, int y, int x) {
  static const double wm[8]  = {0.03125, 0.09375, 0.15625, 0.21875,
                                0.21875, 0.15625, 0.09375, 0.03125};
  static const double w0[8]  = {0.0, 0.0, 0.625/3.5, 0.875/3.5,
                                0.875/3.5, 0.625/3.5, 0.375/3.5, 0.125/3.5};
  static const double w95[8] = {0.125/3.5, 0.375/3.5, 0.625/3.5, 0.875/3.5,
                                0.875/3.5, 0.625/3.5, 0.0, 0.0};
  const double* wy = (y == 0) ? w0 : (y == 95 ? w95 : wm);
  const double* wx = (x == 0) ? w0 : (x == 95 ? w95 : wm);
  double acc = 0.0;
#pragma unroll
  for (int ky = 0; ky < 8; ++ky) {
    double wyv = wy[ky];
    if (wyv == 0.0) continue;
    int jy = 4 * y - 2 + ky;
    const float* row = img + jy * 384;
    double ra = 0.0;
#pragma unroll
    for (int kx = 0; kx < 8; ++kx) {
      double wxv = wx[kx];
      if (wxv == 0.0) continue;
      ra += wxv * (double)row[4 * x - 2 + kx];
    }
    acc += wyv * ra;
  }
  return acc;
}

// Masks: rv, vm = rv*tv (tv recomputed inline per t — fp64 compute is cheap
// relative to anything else), per-block v_sum partials.
// grid: (HW/256, T*B), 1 px/thread.
__global__ __launch_bounds__(256) void k_masks(const float* __restrict__ tvmap,
                                               const float* __restrict__ rvmaps,
                                               float* __restrict__ rv,
                                               float* __restrict__ vm,
                                               float* __restrict__ v_part) {
  int tb = blockIdx.y;          // t*B + b
  int b = tb % B_;
  int p = blockIdx.x * 256 + threadIdx.x;
  int y = p / 96, x = p % 96;
  float tvv = (resize_px(tvmap + (size_t)b * IN_HW_, y, x) > 0.5) ? 1.0f : 0.0f;
  float rvv = (resize_px(rvmaps + (size_t)tb * IN_HW_, y, x) > 0.5) ? 1.0f : 0.0f;
  float vmv = rvv * tvv;
  rv[(size_t)tb * HW_ + p] = rvv;
  vm[(size_t)tb * HW_ + p] = vmv;
  __shared__ float s[256];
  s[threadIdx.x] = vmv;
  __syncthreads();
  for (int k = 128; k > 0; k >>= 1) {
    if (threadIdx.x < (unsigned)k) s[threadIdx.x] += s[threadIdx.x + k];
    __syncthreads();
  }
  if (threadIdx.x == 0) v_part[tb * VPART + blockIdx.x] = s[0];
}

// gs partials: block = (c, chunk, b); t-loop inside so t_feat is read once.
// Single-trip: 256 float4 per chunk, one per thread, 17 streams.
// grid (C, NCHUNK, B) = 4608 blocks (18/CU).
__global__ __launch_bounds__(256) void k_gs(const float* __restrict__ values,
                                            const float* __restrict__ vm,
                                            float* __restrict__ gs_part) {
  int c     = blockIdx.x;
  int chunk = blockIdx.y;
  int b     = blockIdx.z;
  int i = chunk * (HW_ / 4 / NCHUNK) + threadIdx.x;   // 256 f4 per chunk
  float4 a = ((const float4*)(values + ((size_t)b * C_ + c) * HW_))[i];
  float acc[T_];
#pragma unroll
  for (int t = 0; t < T_; ++t) {
    int tb = t * B_ + b;
    float4 m = ((const float4*)(vm + (size_t)tb * HW_))[i];
    float4 r = ((const float4*)(values + ((size_t)(B_ + tb) * C_ + c) * HW_))[i];
    acc[t] = m.x * a.x * r.x + m.y * a.y * r.y + m.z * a.z * r.z + m.w * a.w * r.w;
  }
  // wave reduce each acc, then cross-wave via LDS
  __shared__ float part[4][T_];
  int lane = threadIdx.x & 63, wid = threadIdx.x >> 6;
#pragma unroll
  for (int t = 0; t < T_; ++t) {
    float v = acc[t];
    for (int off = 32; off > 0; off >>= 1) v += __shfl_down(v, off);
    if (lane == 0) part[wid][t] = v;
  }
  __syncthreads();
  if (threadIdx.x < T_) {
    int t = threadIdx.x;
    float v = part[0][t] + part[1][t] + part[2][t] + part[3][t];
    gs_part[((size_t)chunk * (T_ * B_) + (size_t)(t * B_ + b)) * C_ + c] = v;
  }
}

// Epilogue (gs finalize folded in): per-block, 8 lane-groups of 32 reduce
// gs[t] for this b from gs_part/v_part; then per-pixel softmax-match over t,
// c_out, c_mask, t_feat copy.
// grid: (32 ctiles of 4 channels, 9 ptiles of 1024 px, B) x 256, 4 px/thread.
__global__ __launch_bounds__(256) void k_epi(const float* __restrict__ values,
                                             const float* __restrict__ rv,
                                             const float* __restrict__ gs_part,
                                             const float* __restrict__ v_part,
                                             float* __restrict__ out,
                                             float* __restrict__ out_cmask,
                                             float* __restrict__ out_gs) {
  int ctile = blockIdx.x;       // 0..31
  int ptile = blockIdx.y;       // 0..8
  int b     = blockIdx.z;       // 0..3

  // ---- inline gs finalization: group g (32 lanes) handles t = g ----
  __shared__ float gsh[T_];
  {
    int t = threadIdx.x >> 5;           // 0..7
    int lane = threadIdx.x & 31;
    int tb = t * B_ + b;
    float s = 0.f;
    // sum gs_part over (chunk, c): NCHUNK*C_ = 1152 values, lane-strided
    for (int idx = lane; idx < NCHUNK * C_; idx += 32) {
      int ch = idx / C_, c = idx % C_;
      s += gs_part[((size_t)ch * (T_ * B_) + tb) * C_ + c];
    }
    float vs = 0.f;
    for (int k = lane; k < VPART; k += 32) vs += v_part[tb * VPART + k];
    for (int off = 16; off > 0; off >>= 1) {
      s  += __shfl_down(s, off, 32);
      vs += __shfl_down(vs, off, 32);
    }
    if (lane == 0) {
      bool empty = vs < 1e-4f;          // vs is an exact integer count
      float g = (empty ? 0.f : s) / (vs + (empty ? 1.f : 0.f)) / (float)C_;
      gsh[t] = g;
      if (ctile == 0 && ptile == 0) out_gs[t * B_ + b] = g;
    }
  }
  __syncthreads();

  int p0 = ptile * 1024 + threadIdx.x * 4;

  float4 rv4[T_];
#pragma unroll
  for (int t = 0; t < T_; ++t)
    rv4[t] = *(const float4*)(rv + ((size_t)(t * B_ + b)) * HW_ + p0);

  float cm[T_][4];
  float cmask[4];
#pragma unroll
  for (int j = 0; j < 4; ++j) {
    float mv[T_];
    float mx = -1e30f;
#pragma unroll
    for (int t = 0; t < T_; ++t) {
      float rvv = ((const float*)&rv4[t])[j];
      mv[t] = gsh[t] * rvv;
      mx = fmaxf(mx, mv[t]);
    }
    float e[T_];
    float ms = 0.f;
#pragma unroll
    for (int t = 0; t < T_; ++t) {
      float rvv = ((const float*)&rv4[t])[j];
      e[t] = expf(mv[t] - mx) * rvv;
      ms += e[t];
    }
    if (ms < 1e-4f) ms += 1.f;
    float inv = 1.f / ms;
    float cs = 0.f;
#pragma unroll
    for (int t = 0; t < T_; ++t) {
      cm[t][j] = e[t] * inv;
      cs += cm[t][j] * ((const float*)&rv4[t])[j];
    }
    cmask[j] = 1.f - cs;
  }

  size_t outb = (size_t)b * 257 * HW_;
#pragma unroll 1
  for (int cc = 0; cc < 4; ++cc) {
    int c = ctile * 4 + cc;
    // t_feat passthrough (channels 0..127)
    float4 tf = *(const float4*)(values + ((size_t)b * C_ + c) * HW_ + p0);
    *(float4*)(out + outb + (size_t)c * HW_ + p0) = tf;
    // c_out (channels 128..255)
    float4 acc = {0.f, 0.f, 0.f, 0.f};
#pragma unroll
    for (int t = 0; t < T_; ++t) {
      const float4 r = *(const float4*)(values +
          ((size_t)((1 + t) * B_ + b) * C_ + c) * HW_ + p0);
      acc.x += cm[t][0] * r.x;
      acc.y += cm[t][1] * r.y;
      acc.z += cm[t][2] * r.z;
      acc.w += cm[t][3] * r.w;
    }
    *(float4*)(out + outb + (size_t)(C_ + c) * HW_ + p0) = acc;
  }
  if (ctile == 0) {
    float4 cmv = {cmask[0], cmask[1], cmask[2], cmask[3]};
    *(float4*)(out + outb + (size_t)256 * HW_ + p0) = cmv;   // channel 256
    *(float4*)(out_cmask + (size_t)b * HW_ + p0) = cmv;      // output 2
  }
}

extern "C" void kernel_launch(void* const* d_in, const int* in_sizes, int n_in,
                              void* d_out, int out_size, void* d_ws, size_t ws_size,
                              hipStream_t stream) {
  const float* values = (const float*)d_in[0];   // (9,4,128,96,96)
  const float* tvmap  = (const float*)d_in[1];   // (4,1,384,384)
  const float* rvmaps = (const float*)d_in[2];   // (8,4,1,384,384)
  float* out = (float*)d_out;

  // workspace layout (floats)
  float* ws      = (float*)d_ws;
  float* rv      = ws;                              // T*B*HW = 294912
  float* vm      = rv + (size_t)T_ * B_ * HW_;      // 294912
  float* gs_part = vm + (size_t)T_ * B_ * HW_;      // NCHUNK*T*B*C = 36864
  float* v_part  = gs_part + (size_t)NCHUNK * T_ * B_ * C_; // T*B*VPART = 1152

  // output layout: out(4,257,96,96) | c_mask(4,1,96,96) | gs(8,4)
  float* out_cmask = out + (size_t)B_ * 257 * HW_;
  float* out_gs    = out_cmask + (size_t)B_ * HW_;

  hipLaunchKernelGGL(k_masks, dim3(HW_ / 256, T_ * B_), dim3(256), 0, stream,
                     tvmap, rvmaps, rv, vm, v_part);
  hipLaunchKernelGGL(k_gs,    dim3(C_, NCHUNK, B_),     dim3(256), 0, stream,
                     values, vm, gs_part);
  hipLaunchKernelGGL(k_epi,   dim3(32, 9, B_),          dim3(256), 0, stream,
                     values, rv, gs_part, v_part, out, out_cmask, out_gs);
}

// Round 6
// 357.081 us; speedup vs baseline: 1.0255x; 1.0255x over previous
//
#include <hip/hip_runtime.h>
#include <math.h>

#define T_ 8
#define B_ 4
#define C_ 128
#define HW_ 9216        // 96*96
#define IN_HW_ 147456   // 384*384
#define NCHUNK 9        // pixel chunks in k_gs: 9216/4/9 = 256 float4 per chunk
#define VPART 36        // v_sum partials per tb (HW_/256)

// ---------------------------------------------------------------------------
// Bilinear antialias resize 384 -> 96: separable 8-tap triangle filter.
// Raw w_k = {.125,.375,.625,.875,.875,.625,.375,.125}/4; edges renormalized
// over valid taps (/3.5). fp64 to match the numpy reference on knife-edge
// pixels (the >0.5 threshold sits in the bulk of the resized distribution).
// ---------------------------------------------------------------------------
__device__ __forceinline__ double resize_px(const float* __restrict__ img, int y, int x) {
  static const double wm[8]  = {0.03125, 0.09375, 0.15625, 0.21875,
                                0.21875, 0.15625, 0.09375, 0.03125};
  static const double w0[8]  = {0.0, 0.0, 0.625/3.5, 0.875/3.5,
                                0.875/3.5, 0.625/3.5, 0.375/3.5, 0.125/3.5};
  static const double w95[8] = {0.125/3.5, 0.375/3.5, 0.625/3.5, 0.875/3.5,
                                0.875/3.5, 0.625/3.5, 0.0, 0.0};
  const double* wy = (y == 0) ? w0 : (y == 95 ? w95 : wm);
  const double* wx = (x == 0) ? w0 : (x == 95 ? w95 : wm);
  double acc = 0.0;
#pragma unroll
  for (int ky = 0; ky < 8; ++ky) {
    double wyv = wy[ky];
    if (wyv == 0.0) continue;
    int jy = 4 * y - 2 + ky;
    const float* row = img + jy * 384;
    double ra = 0.0;
#pragma unroll
    for (int kx = 0; kx < 8; ++kx) {
      double wxv = wx[kx];
      if (wxv == 0.0) continue;
      ra += wxv * (double)row[4 * x - 2 + kx];
    }
    acc += wyv * ra;
  }
  return acc;
}

// Masks: rv, vm = rv*tv (tv recomputed inline per t — fp64 compute is cheap
// relative to anything else), per-block v_sum partials.
// grid: (HW/256, T*B), 1 px/thread.
__global__ __launch_bounds__(256) void k_masks(const float* __restrict__ tvmap,
                                               const float* __restrict__ rvmaps,
                                               float* __restrict__ rv,
                                               float* __restrict__ vm,
                                               float* __restrict__ v_part) {
  int tb = blockIdx.y;          // t*B + b
  int b = tb % B_;
  int p = blockIdx.x * 256 + threadIdx.x;
  int y = p / 96, x = p % 96;
  float tvv = (resize_px(tvmap + (size_t)b * IN_HW_, y, x) > 0.5) ? 1.0f : 0.0f;
  float rvv = (resize_px(rvmaps + (size_t)tb * IN_HW_, y, x) > 0.5) ? 1.0f : 0.0f;
  float vmv = rvv * tvv;
  rv[(size_t)tb * HW_ + p] = rvv;
  vm[(size_t)tb * HW_ + p] = vmv;
  __shared__ float s[256];
  s[threadIdx.x] = vmv;
  __syncthreads();
  for (int k = 128; k > 0; k >>= 1) {
    if (threadIdx.x < (unsigned)k) s[threadIdx.x] += s[threadIdx.x + k];
    __syncthreads();
  }
  if (threadIdx.x == 0) v_part[tb * VPART + blockIdx.x] = s[0];
}

// gs partials: block = (c, chunk, b); t-loop inside so t_feat is read once.
// Single-trip: 256 float4 per chunk, one per thread, 17 streams.
// grid (C, NCHUNK, B) = 4608 blocks (18/CU).
__global__ __launch_bounds__(256) void k_gs(const float* __restrict__ values,
                                            const float* __restrict__ vm,
                                            float* __restrict__ gs_part) {
  int c     = blockIdx.x;
  int chunk = blockIdx.y;
  int b     = blockIdx.z;
  int i = chunk * (HW_ / 4 / NCHUNK) + threadIdx.x;   // 256 f4 per chunk
  float4 a = ((const float4*)(values + ((size_t)b * C_ + c) * HW_))[i];
  float acc[T_];
#pragma unroll
  for (int t = 0; t < T_; ++t) {
    int tb = t * B_ + b;
    float4 m = ((const float4*)(vm + (size_t)tb * HW_))[i];
    float4 r = ((const float4*)(values + ((size_t)(B_ + tb) * C_ + c) * HW_))[i];
    acc[t] = m.x * a.x * r.x + m.y * a.y * r.y + m.z * a.z * r.z + m.w * a.w * r.w;
  }
  // wave reduce each acc, then cross-wave via LDS
  __shared__ float part[4][T_];
  int lane = threadIdx.x & 63, wid = threadIdx.x >> 6;
#pragma unroll
  for (int t = 0; t < T_; ++t) {
    float v = acc[t];
    for (int off = 32; off > 0; off >>= 1) v += __shfl_down(v, off);
    if (lane == 0) part[wid][t] = v;
  }
  __syncthreads();
  if (threadIdx.x < T_) {
    int t = threadIdx.x;
    float v = part[0][t] + part[1][t] + part[2][t] + part[3][t];
    gs_part[((size_t)chunk * (T_ * B_) + (size_t)(t * B_ + b)) * C_ + c] = v;
  }
}

// Epilogue (gs finalize folded in): per-block, 8 lane-groups of 32 reduce
// gs[t] for this b from gs_part/v_part; then per-pixel softmax-match over t,
// c_out, c_mask, t_feat copy.
// grid: (16 ctiles of 8 channels, 9 ptiles of 1024 px, B) x 256, 4 px/thread.
__global__ __launch_bounds__(256) void k_epi(const float* __restrict__ values,
                                             const float* __restrict__ rv,
                                             const float* __restrict__ gs_part,
                                             const float* __restrict__ v_part,
                                             float* __restrict__ out,
                                             float* __restrict__ out_cmask,
                                             float* __restrict__ out_gs) {
  int ctile = blockIdx.x;       // 0..15
  int ptile = blockIdx.y;       // 0..8
  int b     = blockIdx.z;       // 0..3

  // ---- inline gs finalization: group g (32 lanes) handles t = g ----
  __shared__ float gsh[T_];
  {
    int t = threadIdx.x >> 5;           // 0..7
    int lane = threadIdx.x & 31;
    int tb = t * B_ + b;
    float s = 0.f;
    // sum gs_part over (chunk, c): NCHUNK*C_ = 1152 values, lane-strided
    for (int idx = lane; idx < NCHUNK * C_; idx += 32) {
      int ch = idx / C_, c = idx % C_;
      s += gs_part[((size_t)ch * (T_ * B_) + tb) * C_ + c];
    }
    float vs = 0.f;
    for (int k = lane; k < VPART; k += 32) vs += v_part[tb * VPART + k];
    for (int off = 16; off > 0; off >>= 1) {
      s  += __shfl_down(s, off, 32);
      vs += __shfl_down(vs, off, 32);
    }
    if (lane == 0) {
      bool empty = vs < 1e-4f;          // vs is an exact integer count
      float g = (empty ? 0.f : s) / (vs + (empty ? 1.f : 0.f)) / (float)C_;
      gsh[t] = g;
      if (ctile == 0 && ptile == 0) out_gs[t * B_ + b] = g;
    }
  }
  __syncthreads();

  int p0 = ptile * 1024 + threadIdx.x * 4;

  float4 rv4[T_];
#pragma unroll
  for (int t = 0; t < T_; ++t)
    rv4[t] = *(const float4*)(rv + ((size_t)(t * B_ + b)) * HW_ + p0);

  float cm[T_][4];
  float cmask[4];
#pragma unroll
  for (int j = 0; j < 4; ++j) {
    float mv[T_];
    float mx = -1e30f;
#pragma unroll
    for (int t = 0; t < T_; ++t) {
      float rvv = ((const float*)&rv4[t])[j];
      mv[t] = gsh[t] * rvv;
      mx = fmaxf(mx, mv[t]);
    }
    float e[T_];
    float ms = 0.f;
#pragma unroll
    for (int t = 0; t < T_; ++t) {
      float rvv = ((const float*)&rv4[t])[j];
      e[t] = expf(mv[t] - mx) * rvv;
      ms += e[t];
    }
    if (ms < 1e-4f) ms += 1.f;
    float inv = 1.f / ms;
    float cs = 0.f;
#pragma unroll
    for (int t = 0; t < T_; ++t) {
      cm[t][j] = e[t] * inv;
      cs += cm[t][j] * ((const float*)&rv4[t])[j];
    }
    cmask[j] = 1.f - cs;
  }

  size_t outb = (size_t)b * 257 * HW_;
#pragma unroll 1
  for (int cc = 0; cc < 8; ++cc) {
    int c = ctile * 8 + cc;
    // t_feat passthrough (channels 0..127)
    float4 tf = *(const float4*)(values + ((size_t)b * C_ + c) * HW_ + p0);
    *(float4*)(out + outb + (size_t)c * HW_ + p0) = tf;
    // c_out (channels 128..255)
    float4 acc = {0.f, 0.f, 0.f, 0.f};
#pragma unroll
    for (int t = 0; t < T_; ++t) {
      const float4 r = *(const float4*)(values +
          ((size_t)((1 + t) * B_ + b) * C_ + c) * HW_ + p0);
      acc.x += cm[t][0] * r.x;
      acc.y += cm[t][1] * r.y;
      acc.z += cm[t][2] * r.z;
      acc.w += cm[t][3] * r.w;
    }
    *(float4*)(out + outb + (size_t)(C_ + c) * HW_ + p0) = acc;
  }
  if (ctile == 0) {
    float4 cmv = {cmask[0], cmask[1], cmask[2], cmask[3]};
    *(float4*)(out + outb + (size_t)256 * HW_ + p0) = cmv;   // channel 256
    *(float4*)(out_cmask + (size_t)b * HW_ + p0) = cmv;      // output 2
  }
}

extern "C" void kernel_launch(void* const* d_in, const int* in_sizes, int n_in,
                              void* d_out, int out_size, void* d_ws, size_t ws_size,
                              hipStream_t stream) {
  const float* values = (const float*)d_in[0];   // (9,4,128,96,96)
  const float* tvmap  = (const float*)d_in[1];   // (4,1,384,384)
  const float* rvmaps = (const float*)d_in[2];   // (8,4,1,384,384)
  float* out = (float*)d_out;

  // workspace layout (floats)
  float* ws      = (float*)d_ws;
  float* rv      = ws;                              // T*B*HW = 294912
  float* vm      = rv + (size_t)T_ * B_ * HW_;      // 294912
  float* gs_part = vm + (size_t)T_ * B_ * HW_;      // NCHUNK*T*B*C = 36864
  float* v_part  = gs_part + (size_t)NCHUNK * T_ * B_ * C_; // T*B*VPART = 1152

  // output layout: out(4,257,96,96) | c_mask(4,1,96,96) | gs(8,4)
  float* out_cmask = out + (size_t)B_ * 257 * HW_;
  float* out_gs    = out_cmask + (size_t)B_ * HW_;

  hipLaunchKernelGGL(k_masks, dim3(HW_ / 256, T_ * B_), dim3(256), 0, stream,
                     tvmap, rvmaps, rv, vm, v_part);
  hipLaunchKernelGGL(k_gs,    dim3(C_, NCHUNK, B_),     dim3(256), 0, stream,
                     values, vm, gs_part);
  hipLaunchKernelGGL(k_epi,   dim3(16, 9, B_),          dim3(256), 0, stream,
                     values, rv, gs_part, v_part, out, out_cmask, out_gs);
}